// Round 1
// baseline (2652.764 us; speedup 1.0000x reference)
//
#include <hip/hip_runtime.h>
#include <hip/hip_bf16.h>

typedef __hip_bfloat16 bf16;
typedef __attribute__((ext_vector_type(8))) short short8;
typedef __attribute__((ext_vector_type(4))) float float4v;

#define BSZ 32
#define TT  128
#define IC  16
#define NDIM 512
#define WS_NEED ((size_t)4 * IC * NDIM * NDIM * 2)   // 33.55 MB bf16 packed weights
#define SMEM_BYTES 163840                            // 128 KiB weights + 32 KiB h

// per-channel arrival counters; zeroed by pack_w each run (stream-ordered before es_persist).
// Monotone within a run -> replay-safe, never blocks incorrectly.
__device__ unsigned g_ctr[IC];

__device__ __forceinline__ float sigf(float v) { return 1.0f / (1.0f + expf(-v)); }
__device__ __forceinline__ unsigned f2bfb(float f) {
    bf16 h = __float2bfloat16(f);
    return (unsigned)*reinterpret_cast<unsigned short*>(&h);
}

// ---------------- one-time weight pack: fp32 W -> bf16 MFMA B-fragments ----
// uint4 index = ((blk*16 + kstep)*64 + lane), blk = (g*IC + i)*32 + nt16
// lane frag elems j=0..7:  W_g[i][ kstep*32 + (lane>>4)*8 + j ][ nt16*16 + (lane&15) ]
__global__ void pack_w(const float* __restrict__ Wj, const float* __restrict__ Wi,
                       const float* __restrict__ Wf, const float* __restrict__ Wo,
                       uint4* __restrict__ wpk)
{
    __shared__ float tile[NDIM][17];
    const int blk  = blockIdx.x;
    if (blk == 0 && threadIdx.x < IC) g_ctr[threadIdx.x] = 0u;   // reset barrier counters
    const int nt16 = blk & 31;
    const int i    = (blk >> 5) & 15;
    const int g    = blk >> 9;
    const float* W = (g == 0) ? Wj : (g == 1) ? Wi : (g == 2) ? Wf : Wo;
    const float* base = W + (size_t)i * NDIM * NDIM + nt16 * 16;
    const int tid = threadIdx.x;

    #pragma unroll
    for (int r = 0; r < 2; r++) {
        int n = tid + r * 256;
        const float4* p = (const float4*)(base + (size_t)n * NDIM);
        float4 v0 = p[0], v1 = p[1], v2 = p[2], v3 = p[3];
        float* d = &tile[n][0];
        d[0]=v0.x; d[1]=v0.y; d[2]=v0.z; d[3]=v0.w;
        d[4]=v1.x; d[5]=v1.y; d[6]=v1.z; d[7]=v1.w;
        d[8]=v2.x; d[9]=v2.y; d[10]=v2.z; d[11]=v2.w;
        d[12]=v3.x; d[13]=v3.y; d[14]=v3.z; d[15]=v3.w;
    }
    __syncthreads();
    #pragma unroll
    for (int p = 0; p < 4; p++) {
        int f = p * 256 + tid;
        int kstep = f >> 6, L = f & 63;
        int quad = L >> 4, col = L & 15;
        int nr = kstep * 32 + quad * 8;
        unsigned u[4];
        #pragma unroll
        for (int w = 0; w < 4; w++) {
            unsigned lo = f2bfb(tile[nr + 2 * w][col]);
            unsigned hi = f2bfb(tile[nr + 2 * w + 1][col]);
            u[w] = lo | (hi << 16);
        }
        wpk[(size_t)blk * 1024 + (size_t)kstep * 64 + L] = make_uint4(u[0], u[1], u[2], u[3]);
    }
}

// ---------------- persistent all-timesteps kernel ----------------
// grid (IC, 16): block = (channel i, 32-col tile kt). 1 block/CU (LDS-capped), 256 blocks.
// Weights resident in LDS for all 128 steps; per-channel 16-block atomic barrier between steps.
__launch_bounds__(256, 1)
__global__ void es_persist(
    const float* __restrict__ x,
    const float* __restrict__ Uj, const float* __restrict__ Ui,
    const float* __restrict__ Uf, const float* __restrict__ Uo,
    const uint4* __restrict__ wpk,
    const float* __restrict__ bj, const float* __restrict__ bi,
    const float* __restrict__ bfp, const float* __restrict__ bo,
    float* __restrict__ out)
{
    extern __shared__ unsigned char smem[];
    uint4* w_lds = (uint4*)smem;               // 128 KiB: [ntl][gate][ks][lane] 16B frags
    unsigned char* h_base = smem + 131072;     // 32 KiB: row b at b*1024 B, col-byte ^ ((b&7)<<4)

    const int i   = blockIdx.x;        // channel
    const int kt  = blockIdx.y;        // 32-col tile
    const int tid = threadIdx.x;
    const int wid = tid >> 6, L = tid & 63;
    const int quad = L >> 4, c15 = L & 15;
    const int ntl  = wid & 1;                  // local 16-col tile
    const int nt16 = kt * 2 + ntl;
    const int Mh   = (wid >> 1) * 16;          // batch half

    float* hfin = out + (size_t)BSZ * TT * IC * NDIM;
    float* cfin = hfin + (size_t)BSZ * IC * NDIM;

    // ---- prologue: this block's packed weights -> LDS (once, ~131 KB from L3/HBM)
    #pragma unroll
    for (int f = 0; f < 32; f++) {
        int d = f * 256 + tid;
        int lntl = d >> 12, g = (d >> 10) & 3, ks = (d >> 6) & 15, l = d & 63;
        w_lds[d] = wpk[((size_t)(g * IC + i) * 32 + (kt * 2 + lntl)) * 1024 + (size_t)ks * 64 + l];
    }

    // ---- hoist loop-invariant per-lane scalars into registers
    const int n = nt16 * 16 + c15;
    const size_t un = (size_t)i * NDIM + n;
    const float u0 = Uj[un], u1 = Ui[un], u2 = Uf[un], u3 = Uo[un];
    const float c0 = bj[un], c1 = bi[un], c2 = bfp[un], c3 = bo[un];
    const float a_out = 0.990049834f;          // exp(-0.01)

    float cc[4] = {0.f, 0.f, 0.f, 0.f};        // c-state lives in registers across all steps

    // staging mapping (same as proven step_mfma, plus XOR swizzle)
    const int sb = tid >> 3, sn0 = (tid & 7) * 64;
    const int sx = (sb & 7) << 4;
    unsigned char* hrow_w = h_base + sb * 1024;

    __syncthreads();

    #pragma unroll 1
    for (int t = 0; t < TT; t++) {
        float4v acc0 = {0,0,0,0}, acc1 = {0,0,0,0}, acc2 = {0,0,0,0}, acc3 = {0,0,0,0};

        // x loads depend on no other block: issue before the wait so latency hides under it
        float xv[4];
        #pragma unroll
        for (int r = 0; r < 4; r++)
            xv[r] = x[(size_t)((Mh + quad * 4 + r) * TT + t) * IC + i];

        if (t > 0) {
            // ---- wait for all 16 blocks of channel i to have published h(t-1)
            if (tid == 0) {
                const unsigned target = 16u * (unsigned)t;
                long spins = 0;
                while (__hip_atomic_load(&g_ctr[i], __ATOMIC_RELAXED, __HIP_MEMORY_SCOPE_AGENT) < target) {
                    __builtin_amdgcn_s_sleep(1);
                    if (++spins > 20000000L) break;   // fail loud (bad data), never hang
                }
                (void)__hip_atomic_load(&g_ctr[i], __ATOMIC_ACQUIRE, __HIP_MEMORY_SCOPE_AGENT); // inv caches
            }
            __syncthreads();

            // ---- stage h[:, t-1, i, :] (fp32 global) -> bf16 LDS, XOR-swizzled rows
            {
                const float4* src = (const float4*)(out + ((size_t)(sb * TT + (t - 1)) * IC + i) * NDIM + sn0);
                #pragma unroll
                for (int q = 0; q < 8; q++) {
                    float4 a = src[2 * q], b2 = src[2 * q + 1];
                    unsigned v0 = f2bfb(a.x)  | (f2bfb(a.y)  << 16);
                    unsigned v1 = f2bfb(a.z)  | (f2bfb(a.w)  << 16);
                    unsigned v2 = f2bfb(b2.x) | (f2bfb(b2.y) << 16);
                    unsigned v3 = f2bfb(b2.z) | (f2bfb(b2.w) << 16);
                    *(uint4*)(hrow_w + (((sn0 + q * 8) * 2) ^ sx)) = make_uint4(v0, v1, v2, v3);
                }
            }
            __syncthreads();

            // ---- MFMA: A from swizzled h LDS, B from resident weight LDS
            const int arow = Mh + c15;
            const unsigned char* aptr = h_base + arow * 1024;
            const int ax = (arow & 7) << 4;
            const uint4* wb = w_lds + ntl * 4096 + L;     // gate stride 1024 uint4
            #pragma unroll 4
            for (int ks = 0; ks < 16; ks++) {
                short8 a  = *(const short8*)(aptr + ((ks * 64 + quad * 16) ^ ax));
                short8 b0 = *(const short8*)(wb + ks * 64);
                short8 b1 = *(const short8*)(wb + 1024 + ks * 64);
                short8 b2 = *(const short8*)(wb + 2048 + ks * 64);
                short8 b3 = *(const short8*)(wb + 3072 + ks * 64);
                acc0 = __builtin_amdgcn_mfma_f32_16x16x32_bf16(a, b0, acc0, 0, 0, 0);
                acc1 = __builtin_amdgcn_mfma_f32_16x16x32_bf16(a, b1, acc1, 0, 0, 0);
                acc2 = __builtin_amdgcn_mfma_f32_16x16x32_bf16(a, b2, acc2, 0, 0, 0);
                acc3 = __builtin_amdgcn_mfma_f32_16x16x32_bf16(a, b3, acc3, 0, 0, 0);
            }
        }

        // ---- epilogue (all 4 gates resident in this wave's acc regs)
        #pragma unroll
        for (int r = 0; r < 4; r++) {
            const int b = Mh + quad * 4 + r;    // C-layout row

            float jg = tanhf(acc0[r] + c0 + xv[r] * u0);
            float ig = sigf (acc1[r] + c1 + xv[r] * u1);
            float fg = sigf (acc2[r] + c2 + xv[r] * u2);
            float og = sigf (acc3[r] + c3 + xv[r] * u3);

            float alpha_m = expf(-7.8125e-5f * jg);
            float ro      = expf(-1.5625e-4f * ig);
            float b_ad    = ro * 0.1f + (1.0f - ro) * ig;
            float Bth     = 0.04f + 1.8f * b_ad;

            float hprev = 0.0f;
            if (t > 0)   // coeff (1-alpha)~7.8e-5: bf16 is free (same as prior verified kernel)
                hprev = __bfloat162float(*(const bf16*)(h_base + b * 1024 + ((n * 2) ^ ((b & 7) << 4))));

            float mem   = jg * alpha_m + (1.0f - alpha_m) * hprev - Bth * ig * 0.01f;
            float spike = (mem - Bth) > 0.0f ? 1.0f : 0.0f;
            float mem_o = mem * a_out + (1.0f - a_out) * spike + 0.08f;

            float cn = cc[r] * fg + ig * spike * mem_o;
            float hn = og * tanhf(cn);
            cc[r] = cn;

            out[((size_t)(b * TT + t) * IC + i) * NDIM + n] = hn;
            if (t == TT - 1) {
                size_t sidx = ((size_t)b * IC + i) * NDIM + n;
                cfin[sidx] = cn;
                hfin[sidx] = hn;
            }
        }

        // ---- publish h(t) to the channel group
        if (t < TT - 1) {
            __syncthreads();               // all waves' stores drained to (write-through) L2
            if (tid == 0) {
                __threadfence();           // agent release: L2 writeback for cross-XCD readers
                __hip_atomic_fetch_add(&g_ctr[i], 1u, __ATOMIC_RELEASE, __HIP_MEMORY_SCOPE_AGENT);
            }
        }
    }
}

// ---------------- fallback (proven R5 path, used only if ws too small) ----
#define KT 32
#define NC 64
__launch_bounds__(256)
__global__ void step_kernel_valu(int t,
    const float* __restrict__ x,
    const float* __restrict__ Uj, const float* __restrict__ Ui, const float* __restrict__ Uf, const float* __restrict__ Uo,
    const float* __restrict__ Wj, const float* __restrict__ Wi, const float* __restrict__ Wf, const float* __restrict__ Wo,
    const float* __restrict__ bj, const float* __restrict__ bi, const float* __restrict__ bfp, const float* __restrict__ bo,
    float* __restrict__ out)
{
    __shared__ float w_lds[NC][KT * 4 + 4];
    __shared__ float h_lds[NC][BSZ + 4];
    const int i = blockIdx.x, k0 = blockIdx.y * KT, tid = threadIdx.x;
    const int kl = tid & 31, bg = tid >> 5, kg = k0 + kl;
    float* hfin = out + (size_t)BSZ * TT * IC * NDIM;
    float* cfin = hfin + (size_t)BSZ * IC * NDIM;
    float acc[4][4];
    {
        size_t uidx = (size_t)i * NDIM + kg;
        float u0 = Uj[uidx], u1 = Ui[uidx], u2 = Uf[uidx], u3 = Uo[uidx];
        float c0 = bj[uidx], c1 = bi[uidx], c2 = bfp[uidx], c3 = bo[uidx];
        #pragma unroll
        for (int j = 0; j < 4; j++) {
            int b = bg * 4 + j;
            float xv = x[(size_t)(b * TT + t) * IC + i];
            acc[0][j] = c0 + xv * u0; acc[1][j] = c1 + xv * u1;
            acc[2][j] = c2 + xv * u2; acc[3][j] = c3 + xv * u3;
        }
    }
    if (t > 0) {
        for (int n0 = 0; n0 < NDIM; n0 += NC) {
            __syncthreads();
            {
                int g = tid >> 6, nn = tid & 63;
                const float* Wp = (g == 0) ? Wj : (g == 1) ? Wi : (g == 2) ? Wf : Wo;
                const float4* p = (const float4*)(Wp + ((size_t)i * NDIM + (size_t)(n0 + nn)) * NDIM + k0);
                #pragma unroll
                for (int q = 0; q < 8; q++) {
                    float4 v = p[q];
                    w_lds[nn][(q * 4 + 0) * 4 + g] = v.x; w_lds[nn][(q * 4 + 1) * 4 + g] = v.y;
                    w_lds[nn][(q * 4 + 2) * 4 + g] = v.z; w_lds[nn][(q * 4 + 3) * 4 + g] = v.w;
                }
            }
            {
                int b = tid >> 3, nb = (tid & 7) * 8;
                const float4* ph = (const float4*)(out + ((size_t)(b * TT + (t - 1)) * IC + i) * NDIM + n0 + nb);
                float4 h0 = ph[0], h1 = ph[1];
                h_lds[nb + 0][b] = h0.x; h_lds[nb + 1][b] = h0.y; h_lds[nb + 2][b] = h0.z; h_lds[nb + 3][b] = h0.w;
                h_lds[nb + 4][b] = h1.x; h_lds[nb + 5][b] = h1.y; h_lds[nb + 6][b] = h1.z; h_lds[nb + 7][b] = h1.w;
            }
            __syncthreads();
            #pragma unroll 8
            for (int nn = 0; nn < NC; nn++) {
                float4 wv = *(const float4*)&w_lds[nn][kl * 4];
                float4 hv = *(const float4*)&h_lds[nn][bg * 4];
                acc[0][0] += hv.x * wv.x; acc[1][0] += hv.x * wv.y; acc[2][0] += hv.x * wv.z; acc[3][0] += hv.x * wv.w;
                acc[0][1] += hv.y * wv.x; acc[1][1] += hv.y * wv.y; acc[2][1] += hv.y * wv.z; acc[3][1] += hv.y * wv.w;
                acc[0][2] += hv.z * wv.x; acc[1][2] += hv.z * wv.y; acc[2][2] += hv.z * wv.z; acc[3][2] += hv.z * wv.w;
                acc[0][3] += hv.w * wv.x; acc[1][3] += hv.w * wv.y; acc[2][3] += hv.w * wv.z; acc[3][3] += hv.w * wv.w;
            }
        }
    }
    const float a_out = 0.990049834f;
    #pragma unroll
    for (int j = 0; j < 4; j++) {
        int b = bg * 4 + j;
        size_t sidx = ((size_t)b * IC + i) * NDIM + kg;
        float jg = tanhf(acc[0][j]), ig = sigf(acc[1][j]), fg = sigf(acc[2][j]), og = sigf(acc[3][j]);
        float alpha_m = expf(-7.8125e-5f * jg);
        float ro = expf(-1.5625e-4f * ig);
        float b_ad = ro * 0.1f + (1.0f - ro) * ig;
        float Bth = 0.04f + 1.8f * b_ad;
        float hprev = 0.0f, cprev = 0.0f;
        if (t > 0) { hprev = out[((size_t)(b * TT + (t - 1)) * IC + i) * NDIM + kg]; cprev = cfin[sidx]; }
        float mem = jg * alpha_m + (1.0f - alpha_m) * hprev - Bth * ig * 0.01f;
        float spike = (mem - Bth) > 0.0f ? 1.0f : 0.0f;
        float mem_o = mem * a_out + (1.0f - a_out) * spike + 0.08f;
        float cn = cprev * fg + ig * spike * mem_o;
        float hn = og * tanhf(cn);
        cfin[sidx] = cn;
        out[((size_t)(b * TT + t) * IC + i) * NDIM + kg] = hn;
        if (t == TT - 1) hfin[sidx] = hn;
    }
}

extern "C" void kernel_launch(void* const* d_in, const int* in_sizes, int n_in,
                              void* d_out, int out_size, void* d_ws, size_t ws_size,
                              hipStream_t stream) {
    const float* x   = (const float*)d_in[0];
    const float* Uj  = (const float*)d_in[1];
    const float* Ui_ = (const float*)d_in[2];
    const float* Uf  = (const float*)d_in[3];
    const float* Uo  = (const float*)d_in[4];
    const float* Wj  = (const float*)d_in[5];
    const float* Wi  = (const float*)d_in[6];
    const float* Wf  = (const float*)d_in[7];
    const float* Wo  = (const float*)d_in[8];
    const float* bj  = (const float*)d_in[9];
    const float* bi_ = (const float*)d_in[10];
    const float* bf_ = (const float*)d_in[11];
    const float* bo  = (const float*)d_in[12];
    float* out = (float*)d_out;

    if (ws_size >= WS_NEED) {
        static bool attr_set = false;
        if (!attr_set) {   // opt-in to 160 KiB dynamic LDS (host-side, not captured)
            (void)hipFuncSetAttribute((const void*)es_persist,
                                      hipFuncAttributeMaxDynamicSharedMemorySize, SMEM_BYTES);
            attr_set = true;
        }
        pack_w<<<dim3(2048), dim3(256), 0, stream>>>(Wj, Wi, Wf, Wo, (uint4*)d_ws);
        es_persist<<<dim3(IC, 16), dim3(256), SMEM_BYTES, stream>>>(
            x, Uj, Ui_, Uf, Uo, (const uint4*)d_ws, bj, bi_, bf_, bo, out);
    } else {
        for (int t = 0; t < TT; t++) {
            step_kernel_valu<<<dim3(IC, NDIM / KT), dim3(256), 0, stream>>>(
                t, x, Uj, Ui_, Uf, Uo, Wj, Wi, Wf, Wo, bj, bi_, bf_, bo, out);
        }
    }
}